// Round 3
// baseline (75.157 us; speedup 1.0000x reference)
//
#include <hip/hip_runtime.h>

#define NROW 4096      // 64*64 patch positions
#define NCOL 4225      // 65*65 plane
#define BATCH 8
#define MAGIC 0x13579BDFu

// ws layout: float partial[256]; unsigned flags[256];

__global__ void __launch_bounds__(512) k_fused(const float* __restrict__ x,
                                               const float* __restrict__ proj_w,
                                               const float* __restrict__ proj_b,
                                               float* __restrict__ out,
                                               float* __restrict__ partial,
                                               unsigned* __restrict__ flags) {
    __shared__ float cs_sh[NCOL];   // batch-summed plane
    __shared__ float s_sh[NROW];    // tanh scalars
    __shared__ float c_sh[16];      // per-row softmax results
    const int tid = threadIdx.x;
    const int bid = blockIdx.x;

    // phase 1: colsum[p] = sum_b x[b,p]  (coalesced; 512 threads, 2 waves/SIMD
    // to hide the ~200-300cyc L2 latency)
    for (int p = tid; p < NCOL; p += 512) {
        float v = 0.0f;
#pragma unroll
        for (int b = 0; b < BATCH; ++b) v += x[b * NCOL + p];
        cs_sh[p] = v;
    }
    __syncthreads();

    // phase 2: s[n] = tanh(2x2 patch sum / 32) — 8 per thread
#pragma unroll
    for (int k = 0; k < 8; ++k) {
        int n = tid + (k << 9);
        int i = n >> 6, j = n & 63;
        const float* c = &cs_sh[i * 65 + j];
        s_sh[n] = tanhf((c[0] + c[1] + c[65] + c[66]) * (1.0f / 32.0f));
    }
    __syncthreads();

    // phase 3: 16 rows/block, 32 lanes/row; stride-32 m-index.
    // In a wave64, lanes L and L+32 read identical LDS addresses (broadcast)
    // and lanes 0-31 hit 32 distinct banks -> conflict-free.
    const int row = (bid << 4) + (tid >> 5);
    const int m0  = tid & 31;
    const float t = 8.0f * 1.4426950408889634f * s_sh[row];  // fold log2(e)
    float num = 0.0f, den = 0.0f;
#pragma unroll 8
    for (int k = 0; k < 128; ++k) {
        float sm = s_sh[m0 + (k << 5)];
        float e  = exp2f(t * sm);   // |arg| < 11.6, no max-subtraction needed
        num += e * sm;
        den += e;
    }
#pragma unroll
    for (int off = 16; off; off >>= 1) {
        num += __shfl_down(num, off, 32);
        den += __shfl_down(den, off, 32);
    }
    if (m0 == 0) c_sh[tid >> 5] = num / den;
    __syncthreads();

    // phase 4: publish block partial (atomic RMW -> device-coherent; no init needed)
    if (tid == 0) {
        float bs = 0.0f;
#pragma unroll
        for (int r = 0; r < 16; ++r) bs += c_sh[r];
        atomicExch(&partial[bid], bs);
        __threadfence();
        atomicExch(&flags[bid], MAGIC);
    }

    // phase 5: block 0, wave 0 waits for all partials and finalizes.
    // All other blocks retire unconditionally -> no deadlock under any scheduling.
    if (bid == 0 && tid < 64) {
#pragma unroll
        for (int q = 0; q < 4; ++q) {
            int i = tid + (q << 6);
            while (atomicAdd(&flags[i], 0u) != MAGIC) {}
        }
        __threadfence();
        float acc_c = 0.0f;
#pragma unroll
        for (int q = 0; q < 4; ++q) {
            int i = tid + (q << 6);
            acc_c += atomicAdd(&partial[i], 0.0f);  // coherent read
        }
        float pw = proj_w[tid];  // 64 lanes, one weight each
#pragma unroll
        for (int off = 32; off; off >>= 1) {
            acc_c += __shfl_down(acc_c, off, 64);
            pw    += __shfl_down(pw, off, 64);
        }
        if (tid == 0) {
            float o = (acc_c * (1.0f / (float)NROW)) * pw + proj_b[0];
#pragma unroll
            for (int b = 0; b < BATCH; ++b) out[b] = o;
        }
    }
}

extern "C" void kernel_launch(void* const* d_in, const int* in_sizes, int n_in,
                              void* d_out, int out_size, void* d_ws, size_t ws_size,
                              hipStream_t stream) {
    const float* x      = (const float*)d_in[0];
    const float* proj_w = (const float*)d_in[1];
    const float* proj_b = (const float*)d_in[2];
    float* out = (float*)d_out;

    float*    partial = (float*)d_ws;
    unsigned* flags   = (unsigned*)(partial + 256);

    k_fused<<<256, 512, 0, stream>>>(x, proj_w, proj_b, out, partial, flags);
}

// Round 4
// 70.032 us; speedup vs baseline: 1.0732x; 1.0732x over previous
//
#include <hip/hip_runtime.h>

#define NROW 4096      // 64*64 patch positions
#define NCOL 4225      // 65*65 plane
#define BATCH 8
#define MAGIC 0x13579BDFu

// ws layout: float partial[256]; unsigned flags[256];

// fast tanh for |x| <~ 4: tanh(x) = 1 - 2/(e^{2x}+1), e^{2x} via exp2
__device__ __forceinline__ float fast_tanh(float x) {
    float e = __builtin_exp2f(2.885390082f * x);   // 2*log2(e)*x
    return 1.0f - 2.0f / (e + 1.0f);
}

__global__ void __launch_bounds__(256) k_fused(const float* __restrict__ x,
                                               const float* __restrict__ proj_w,
                                               const float* __restrict__ proj_b,
                                               float* __restrict__ out,
                                               float* __restrict__ partial,
                                               unsigned* __restrict__ flags) {
    __shared__ float cs_sh[NCOL];   // batch-summed plane
    __shared__ float s_sh[NROW];    // tanh scalars
    __shared__ float c_sh[16];      // per-row softmax results
    const int tid = threadIdx.x;
    const int bid = blockIdx.x;

    // phase 1: colsum[p] = sum_b x[b,p]; fully unrolled 16x body + 129 tail
    // (independent loads batched -> max outstanding vmcnt)
#pragma unroll
    for (int k = 0; k < 16; ++k) {
        int p = tid + (k << 8);
        float v = 0.0f;
#pragma unroll
        for (int b = 0; b < BATCH; ++b) v += x[b * NCOL + p];
        cs_sh[p] = v;
    }
    if (tid < NCOL - NROW) {       // 129-element tail
        int p = NROW + tid;
        float v = 0.0f;
#pragma unroll
        for (int b = 0; b < BATCH; ++b) v += x[b * NCOL + p];
        cs_sh[p] = v;
    }
    __syncthreads();

    // phase 2: s[n] = tanh(2x2 patch sum / 32) — 16 per thread, branch-free tanh
#pragma unroll
    for (int k = 0; k < 16; ++k) {
        int n = tid + (k << 8);
        int i = n >> 6, j = n & 63;
        const float* c = &cs_sh[i * 65 + j];
        s_sh[n] = fast_tanh((c[0] + c[1] + c[65] + c[66]) * (1.0f / 32.0f));
    }
    __syncthreads();

    // phase 3: 16 rows/block, 16 lanes/row; stride-16 m-index -> conflict-free
    const int row = (bid << 4) + (tid >> 4);
    const int m0  = tid & 15;
    const float t = 8.0f * 1.4426950408889634f * s_sh[row];  // fold log2(e)
    float num = 0.0f, den = 0.0f;
#pragma unroll 8
    for (int k = 0; k < 256; ++k) {
        float sm = s_sh[m0 + (k << 4)];
        float e  = __builtin_exp2f(t * sm);  // |arg| < 11.6, no max-subtract
        num += e * sm;
        den += e;
    }
#pragma unroll
    for (int off = 8; off; off >>= 1) {
        num += __shfl_down(num, off, 16);
        den += __shfl_down(den, off, 16);
    }
    if (m0 == 0) c_sh[tid >> 4] = num / den;
    __syncthreads();

    // phase 4: publish block partial (atomic RMW -> device-coherent; no init needed)
    if (tid == 0) {
        float bs = 0.0f;
#pragma unroll
        for (int r = 0; r < 16; ++r) bs += c_sh[r];
        atomicExch(&partial[bid], bs);
        __threadfence();
        atomicExch(&flags[bid], MAGIC);
    }

    // phase 5: block 0, wave 0 waits for all partials and finalizes.
    // All other blocks retire unconditionally -> no deadlock under any scheduling.
    if (bid == 0 && tid < 64) {
#pragma unroll
        for (int q = 0; q < 4; ++q) {
            int i = tid + (q << 6);
            while (atomicAdd(&flags[i], 0u) != MAGIC) {}
        }
        __threadfence();
        float acc_c = 0.0f;
#pragma unroll
        for (int q = 0; q < 4; ++q) {
            int i = tid + (q << 6);
            acc_c += atomicAdd(&partial[i], 0.0f);  // coherent read
        }
        float pw = proj_w[tid];  // 64 lanes, one weight each
#pragma unroll
        for (int off = 32; off; off >>= 1) {
            acc_c += __shfl_down(acc_c, off, 64);
            pw    += __shfl_down(pw, off, 64);
        }
        if (tid == 0) {
            float o = (acc_c * (1.0f / (float)NROW)) * pw + proj_b[0];
#pragma unroll
            for (int b = 0; b < BATCH; ++b) out[b] = o;
        }
    }
}

extern "C" void kernel_launch(void* const* d_in, const int* in_sizes, int n_in,
                              void* d_out, int out_size, void* d_ws, size_t ws_size,
                              hipStream_t stream) {
    const float* x      = (const float*)d_in[0];
    const float* proj_w = (const float*)d_in[1];
    const float* proj_b = (const float*)d_in[2];
    float* out = (float*)d_out;

    float*    partial = (float*)d_ws;
    unsigned* flags   = (unsigned*)(partial + 256);

    k_fused<<<256, 256, 0, stream>>>(x, proj_w, proj_b, out, partial, flags);
}